// Round 4
// baseline (154.438 us; speedup 1.0000x reference)
//
#include <hip/hip_runtime.h>
#include <math.h>

#define TEMP_INV 10.0f     // 1 / TEMPERATURE
#define EPSN 1e-8f
#define NPART 256          // grid size = #partials (1 block/CU nominal)
#define LOSS_BLOCKS 32     // blocks that continue into the loss phase

// 1 / max(sqrt(ss), EPSN) == rsqrt(max(ss, EPSN^2)), Newton-refined to fp32.
__device__ __forceinline__ float inv_norm(float ss) {
    float x = fmaxf(ss, EPSN * EPSN);
    float y = rsqrtf(x);
    return y * (1.5f - 0.5f * x * y * y);
}

// Four independent butterflies interleaved so cross-lane latencies overlap.
__device__ __forceinline__ void wave_sum4(float& v0, float& v1, float& v2, float& v3) {
    #pragma unroll
    for (int off = 32; off > 0; off >>= 1) {
        v0 += __shfl_xor(v0, off, 64);
        v1 += __shfl_xor(v1, off, 64);
        v2 += __shfl_xor(v2, off, 64);
        v3 += __shfl_xor(v3, off, 64);
    }
}

// Fused kernel. Phase 1 (all 256 blocks) = former k_memsum: partial
// column-sums of the row-normalized memory bank -> P[block][128].
// Then a device-scope counter barrier (release/acquire). Blocks >=32 retire;
// blocks 0..31 run the former k_loss verbatim (redundant P reduce -> S,
// per-sample loss, one atomic per block into out[0]).
//
// Deadlock-safety by construction: __launch_bounds__(1024, 8) caps VGPR at
// 64/wave -> 2 blocks/CU capacity -> all 256 blocks resident simultaneously
// no matter how the dispatcher packs them, so spinners can never starve a
// not-yet-dispatched block. LDS: 16KB (sacc) + ~4.6KB (phase 2) = 20.6KB,
// fits 2 blocks/CU easily.
//
// Fast path uses a sliding 4-deep load window (issue k+4 before processing k)
// instead of 8 live float4s, to fit the 64-VGPR cap without spills while
// keeping 4KB/wave in flight (per-CU in-flight ~64KB >> BW*latency ~22KB).
// FP reduction orders are identical to the two-kernel version.
__global__ __launch_bounds__(1024, 8) void k_fused(
        const float4*  __restrict__ mem4,
        const float2*  __restrict__ real,
        const float2*  __restrict__ pert,
        float*         __restrict__ P,
        unsigned int*  __restrict__ counter,
        float*         __restrict__ out,
        int M, int N, float invN) {
    const int tid = threadIdx.x;
    if (blockIdx.x == 0 && tid == 0) out[0] = 0.0f;   // consumed only after barrier

    // ---------------- phase 1: memory-bank column sums ----------------
    const int lane = tid & 63;
    const int w    = tid >> 6;                 // 0..15
    const int half = lane >> 5;                // 0: row 2p, 1: row 2p+1
    const int sl   = lane & 31;                // float4 index within row
    const int gw   = blockIdx.x * 16 + w;
    const int GW   = gridDim.x * 16;           // 4096
    const int P2   = M >> 1;                   // row pairs (32768)

    float a0 = 0.f, a1 = 0.f, a2 = 0.f, a3 = 0.f;

    int p = gw;
    if (P2 == GW * 8) {                        // exact-shape fast path
        float4 v[8];
        #pragma unroll
        for (int k = 0; k < 4; ++k)
            v[k] = mem4[(size_t)(2 * (gw + k * GW) + half) * 32 + sl];
        #pragma unroll
        for (int k = 0; k < 8; ++k) {
            if (k + 4 < 8)                     // keep a 4-deep window in flight
                v[k + 4] = mem4[(size_t)(2 * (gw + (k + 4) * GW) + half) * 32 + sl];
            float ss = v[k].x * v[k].x + v[k].y * v[k].y
                     + v[k].z * v[k].z + v[k].w * v[k].w;
            #pragma unroll
            for (int off = 16; off > 0; off >>= 1)
                ss += __shfl_xor(ss, off, 64); // stays in own 32-group
            float inv = inv_norm(ss);
            a0 += v[k].x * inv; a1 += v[k].y * inv;
            a2 += v[k].z * inv; a3 += v[k].w * inv;
        }
        p = P2;
    }
    for (; p < P2; p += GW) {                  // generic remainder path
        float4 v = mem4[(size_t)(2 * p + half) * 32 + sl];
        float ss = v.x * v.x + v.y * v.y + v.z * v.z + v.w * v.w;
        #pragma unroll
        for (int off = 16; off > 0; off >>= 1)
            ss += __shfl_xor(ss, off, 64);
        float inv = inv_norm(ss);
        a0 += v.x * inv; a1 += v.y * inv; a2 += v.z * inv; a3 += v.w * inv;
    }
    if ((M & 1) && gw == 0 && half == 0) {     // odd trailing row (not at M=65536)
        float4 v = mem4[(size_t)(M - 1) * 32 + sl];
        float ss = v.x * v.x + v.y * v.y + v.z * v.z + v.w * v.w;
        #pragma unroll
        for (int off = 16; off > 0; off >>= 1)
            ss += __shfl_xor(ss, off, 64);
        float inv = inv_norm(ss);
        a0 += v.x * inv; a1 += v.y * inv; a2 += v.z * inv; a3 += v.w * inv;
    }

    __shared__ float sacc[16][2][128];
    ((float4*)sacc[w][half])[sl] = make_float4(a0, a1, a2, a3);
    __syncthreads();
    if (tid < 128) {
        float s = 0.f;
        #pragma unroll
        for (int i = 0; i < 16; ++i)
            s += sacc[i][0][tid] + sacc[i][1][tid];
        P[blockIdx.x * 128 + tid] = s;
    }

    // ---------------- grid barrier ----------------
    // Each writing thread fences its own stores to agent scope, syncthreads
    // orders them before tid0's release-add; readers acquire + fence.
    __threadfence();
    __syncthreads();
    if (tid == 0)
        __hip_atomic_fetch_add(counter, 1u, __ATOMIC_RELEASE,
                               __HIP_MEMORY_SCOPE_AGENT);
    if (blockIdx.x >= LOSS_BLOCKS) return;     // 224 blocks retire here
    if (tid == 0) {
        while (__hip_atomic_load(counter, __ATOMIC_ACQUIRE,
                                 __HIP_MEMORY_SCOPE_AGENT) < (unsigned)NPART)
            __builtin_amdgcn_s_sleep(8);
    }
    __syncthreads();
    __threadfence();                           // acquire side for all threads

    // ---------------- phase 2: former k_loss, verbatim ----------------
    __shared__ float red[8][128];
    __shared__ float ssum[128];
    {
        const int d = tid & 127;
        const int g = tid >> 7;                // 0..7, 32 P-rows each
        float acc = 0.f;
        #pragma unroll
        for (int j = 0; j < 32; ++j)
            acc += P[(g * 32 + j) * 128 + d];  // coalesced per j
        red[g][d] = acc;
    }
    __syncthreads();
    if (tid < 128) {
        float v = 0.f;
        #pragma unroll
        for (int i = 0; i < 8; ++i) v += red[i][tid];
        ssum[tid] = v;
    }
    __syncthreads();

    const int gw2 = blockIdx.x * 16 + w;       // 0..511
    const int GW2 = LOSS_BLOCKS * 16;          // 512
    const float2 sv = make_float2(ssum[2 * lane], ssum[2 * lane + 1]);

    float lsum = 0.f;
    for (int n = gw2; n < N; n += GW2) {       // 2 iterations at N=1024
        float2 r = real[n * 64 + lane];
        float2 q = pert[n * 64 + lane];
        float ssr = r.x * r.x + r.y * r.y;
        float ssp = q.x * q.x + q.y * q.y;
        float drp = r.x * q.x + r.y * q.y;
        float drs = r.x * sv.x + r.y * sv.y;
        wave_sum4(ssr, ssp, drp, drs);         // 4 chains overlap
        float inr = inv_norm(ssr);             // 1/max(||r||,eps)
        float inp = inv_norm(ssp);             // 1/max(||p||,eps)
        float pos = drp * inr * inp * TEMP_INV;
        float neg = drs * inr * TEMP_INV;
        float mx  = fmaxf(pos, neg);
        float lse = mx + __logf(__expf(pos - mx) + __expf(neg - mx));
        lsum += lse - pos;                     // identical on all lanes
    }

    __shared__ float wl[16];
    if (lane == 0) wl[w] = lsum;
    __syncthreads();
    if (tid == 0) {
        float v = 0.f;
        #pragma unroll
        for (int i = 0; i < 16; ++i) v += wl[i];
        atomicAdd(out, v * invN);              // 32 atomics total, device scope
    }
}

extern "C" void kernel_launch(void* const* d_in, const int* in_sizes, int n_in,
                              void* d_out, int out_size, void* d_ws, size_t ws_size,
                              hipStream_t stream) {
    const float* real = (const float*)d_in[0];   // [N,128]
    const float* pert = (const float*)d_in[1];   // [N,128]
    const float* memb = (const float*)d_in[2];   // [M,128]
    float* out = (float*)d_out;

    const int D = 128;
    const int N = in_sizes[0] / D;               // 1024
    const int M = in_sizes[2] / D;               // 65536

    float* P = (float*)d_ws;                     // [NPART][128]
    unsigned int* counter =
        (unsigned int*)((char*)d_ws + (size_t)NPART * 128 * sizeof(float));

    // ws is poisoned between iterations -> re-zero the barrier counter each
    // launch (stream-ordered 4-byte memset; graph-capturable).
    hipMemsetAsync(counter, 0, sizeof(unsigned int), stream);

    k_fused<<<NPART, 1024, 0, stream>>>((const float4*)memb,
                                        (const float2*)real, (const float2*)pert,
                                        P, counter, out, M, N, 1.0f / (float)N);
}

// Round 5
// 84.533 us; speedup vs baseline: 1.8270x; 1.8270x over previous
//
#include <hip/hip_runtime.h>
#include <math.h>

#define TEMP_INV 10.0f     // 1 / TEMPERATURE
#define EPSN 1e-8f
#define NPART 256          // K1 grid = #partials (1 block/CU; measured best)

// 1 / max(sqrt(ss), EPSN) == rsqrt(max(ss, EPSN^2)), Newton-refined to fp32.
__device__ __forceinline__ float inv_norm(float ss) {
    float x = fmaxf(ss, EPSN * EPSN);
    float y = rsqrtf(x);
    return y * (1.5f - 0.5f * x * y * y);
}

// Four independent butterflies interleaved so cross-lane latencies overlap.
__device__ __forceinline__ void wave_sum4(float& v0, float& v1, float& v2, float& v3) {
    #pragma unroll
    for (int off = 32; off > 0; off >>= 1) {
        v0 += __shfl_xor(v0, off, 64);
        v1 += __shfl_xor(v1, off, 64);
        v2 += __shfl_xor(v2, off, 64);
        v3 += __shfl_xor(v3, off, 64);
    }
}

// K1: partial column-sums of the row-normalized memory bank (R1 binary —
// best measured config, 83.26us). Pair-of-rows-per-wave: lanes 0-31 = row 2p,
// lanes 32-63 = row 2p+1, one dwordx4 wave-load = one full row pair (1KB).
// Norm butterfly stays within each 32-lane half. Fast path fully unrolled:
// 8 pairs/wave, all 8KB in flight at once. grid 256 x 1024 = 4096 waves.
// NOTE (R4 lesson): do NOT fuse K1/K2 with a spin barrier — agent-scope
// acquire polling can read a stale per-XCD L2 line and stall ~80us.
// Block 0 also zeroes out[0] for K2's atomic accumulation (stream-ordered).
__global__ __launch_bounds__(1024) void k_memsum(const float4* __restrict__ mem4,
                                                 float* __restrict__ P,
                                                 float* __restrict__ out, int M) {
    const int tid  = threadIdx.x;
    if (blockIdx.x == 0 && tid == 0) out[0] = 0.0f;

    const int lane = tid & 63;
    const int w    = tid >> 6;                 // 0..15
    const int half = lane >> 5;                // 0: row 2p, 1: row 2p+1
    const int sl   = lane & 31;                // float4 index within row
    const int gw   = blockIdx.x * 16 + w;
    const int GW   = gridDim.x * 16;           // 4096
    const int P2   = M >> 1;                   // row pairs (32768)

    float a0 = 0.f, a1 = 0.f, a2 = 0.f, a3 = 0.f;

    int p = gw;
    if (P2 == GW * 8) {                        // exact-shape fast path
        float4 v[8];
        #pragma unroll
        for (int k = 0; k < 8; ++k)
            v[k] = mem4[(size_t)(2 * (gw + k * GW) + half) * 32 + sl];
        float ss[8];
        #pragma unroll
        for (int k = 0; k < 8; ++k)
            ss[k] = v[k].x * v[k].x + v[k].y * v[k].y
                  + v[k].z * v[k].z + v[k].w * v[k].w;
        #pragma unroll
        for (int off = 16; off > 0; off >>= 1) {
            #pragma unroll
            for (int k = 0; k < 8; ++k)
                ss[k] += __shfl_xor(ss[k], off, 64);   // stays in own 32-group
        }
        #pragma unroll
        for (int k = 0; k < 8; ++k) {
            float inv = inv_norm(ss[k]);
            a0 += v[k].x * inv; a1 += v[k].y * inv;
            a2 += v[k].z * inv; a3 += v[k].w * inv;
        }
        p = P2;
    }
    for (; p < P2; p += GW) {                  // generic remainder path
        float4 v = mem4[(size_t)(2 * p + half) * 32 + sl];
        float ss = v.x * v.x + v.y * v.y + v.z * v.z + v.w * v.w;
        #pragma unroll
        for (int off = 16; off > 0; off >>= 1)
            ss += __shfl_xor(ss, off, 64);
        float inv = inv_norm(ss);
        a0 += v.x * inv; a1 += v.y * inv; a2 += v.z * inv; a3 += v.w * inv;
    }
    // odd trailing row (not taken at M=65536)
    if ((M & 1) && gw == 0 && half == 0) {
        float4 v = mem4[(size_t)(M - 1) * 32 + sl];
        float ss = v.x * v.x + v.y * v.y + v.z * v.z + v.w * v.w;
        #pragma unroll
        for (int off = 16; off > 0; off >>= 1)
            ss += __shfl_xor(ss, off, 64);
        float inv = inv_norm(ss);
        a0 += v.x * inv; a1 += v.y * inv; a2 += v.z * inv; a3 += v.w * inv;
    }

    __shared__ float sacc[16][2][128];
    ((float4*)sacc[w][half])[sl] = make_float4(a0, a1, a2, a3);
    __syncthreads();
    if (tid < 128) {
        float s = 0.f;
        #pragma unroll
        for (int i = 0; i < 16; ++i)
            s += sacc[i][0][tid] + sacc[i][1][tid];
        P[blockIdx.x * 128 + tid] = s;
    }
}

// K2: each block redundantly reduces P[256][128] -> S in LDS with a fully
// unrolled 8-group split (32 outstanding loads/thread, one latency window),
// then 16 waves/block do the per-sample loss.
// TWEAK vs R1: the loss-loop's real/pert operands (2 iterations at N=1024,
// 8 VGPRs) are prefetched BEFORE the P-reduce so their HBM latency hides
// under the 32-load reduce window instead of serializing after the sync.
// FP accumulation order identical to R1 -> bit-identical result.
// grid 32 x 1024 threads.
__global__ __launch_bounds__(1024) void k_loss(const float2* __restrict__ real,
                                               const float2* __restrict__ pert,
                                               const float* __restrict__ P,
                                               float* __restrict__ out,
                                               int N, float invN) {
    const int t    = threadIdx.x;
    const int lane = t & 63;
    const int w    = t >> 6;                   // 0..15
    const int gw   = blockIdx.x * 16 + w;      // 0..511
    const int GW   = gridDim.x * 16;           // 512

    // prefetch loss operands for the first two n-iterations
    const int n0 = gw, n1 = gw + GW;
    const bool h0 = n0 < N, h1 = n1 < N;
    float2 r0 = make_float2(0.f, 0.f), q0 = r0, r1 = r0, q1 = r0;
    if (h0) { r0 = real[n0 * 64 + lane]; q0 = pert[n0 * 64 + lane]; }
    if (h1) { r1 = real[n1 * 64 + lane]; q1 = pert[n1 * 64 + lane]; }

    __shared__ float red[8][128];
    __shared__ float s[128];
    {
        const int d = t & 127;
        const int g = t >> 7;                  // 0..7, 32 rows each
        float acc = 0.f;
        #pragma unroll
        for (int j = 0; j < 32; ++j)
            acc += P[(g * 32 + j) * 128 + d];  // coalesced per j, 32 in flight
        red[g][d] = acc;
    }
    __syncthreads();
    if (t < 128) {
        float v = 0.f;
        #pragma unroll
        for (int i = 0; i < 8; ++i) v += red[i][t];
        s[t] = v;
    }
    __syncthreads();

    const float2 sv = make_float2(s[2 * lane], s[2 * lane + 1]);

    float lsum = 0.f;
    #pragma unroll
    for (int it = 0; it < 2; ++it) {           // the two prefetched iterations
        if (it == 0 ? !h0 : !h1) continue;
        float2 r = (it == 0) ? r0 : r1;
        float2 q = (it == 0) ? q0 : q1;
        float ssr = r.x * r.x + r.y * r.y;
        float ssp = q.x * q.x + q.y * q.y;
        float drp = r.x * q.x + r.y * q.y;
        float drs = r.x * sv.x + r.y * sv.y;
        wave_sum4(ssr, ssp, drp, drs);         // 4 chains overlap
        float inr = inv_norm(ssr);             // 1/max(||r||,eps)
        float inp = inv_norm(ssp);             // 1/max(||p||,eps)
        float pos = drp * inr * inp * TEMP_INV;
        float neg = drs * inr * TEMP_INV;
        float mx  = fmaxf(pos, neg);
        float lse = mx + __logf(__expf(pos - mx) + __expf(neg - mx));
        lsum += lse - pos;                     // identical on all lanes
    }
    for (int n = gw + 2 * GW; n < N; n += GW) { // generic tail (empty at N=1024)
        float2 r = real[n * 64 + lane];
        float2 q = pert[n * 64 + lane];
        float ssr = r.x * r.x + r.y * r.y;
        float ssp = q.x * q.x + q.y * q.y;
        float drp = r.x * q.x + r.y * q.y;
        float drs = r.x * sv.x + r.y * sv.y;
        wave_sum4(ssr, ssp, drp, drs);
        float inr = inv_norm(ssr);
        float inp = inv_norm(ssp);
        float pos = drp * inr * inp * TEMP_INV;
        float neg = drs * inr * TEMP_INV;
        float mx  = fmaxf(pos, neg);
        float lse = mx + __logf(__expf(pos - mx) + __expf(neg - mx));
        lsum += lse - pos;
    }

    __shared__ float wl[16];
    if (lane == 0) wl[w] = lsum;
    __syncthreads();
    if (t == 0) {
        float v = 0.f;
        #pragma unroll
        for (int i = 0; i < 16; ++i) v += wl[i];
        atomicAdd(out, v * invN);              // 32 atomics total, device scope
    }
}

extern "C" void kernel_launch(void* const* d_in, const int* in_sizes, int n_in,
                              void* d_out, int out_size, void* d_ws, size_t ws_size,
                              hipStream_t stream) {
    const float* real = (const float*)d_in[0];   // [N,128]
    const float* pert = (const float*)d_in[1];   // [N,128]
    const float* memb = (const float*)d_in[2];   // [M,128]
    float* out = (float*)d_out;

    const int D = 128;
    const int N = in_sizes[0] / D;               // 1024
    const int M = in_sizes[2] / D;               // 65536

    float* P = (float*)d_ws;                     // [NPART][128]

    k_memsum<<<NPART, 1024, 0, stream>>>((const float4*)memb, P, out, M);
    k_loss<<<32, 1024, 0, stream>>>((const float2*)real, (const float2*)pert,
                                    P, out, N, 1.0f / (float)N);
}